// Round 8
// baseline (807.072 us; speedup 1.0000x reference)
//
#include <hip/hip_runtime.h>
#include <stdint.h>

#define F_NODE 128
#define F_EDGE 32
#define HID    128
#define OUTF   64

#define NBMAX  1024     // max coarse buckets (supports N <= 131072)
#define CE     16384    // edges per chunk for decode/binscat blocks

// ---------------------------------------------------------------------------
// Preprocessing
// ---------------------------------------------------------------------------

// Detect int64 vs int32 edge_index AND zero the coarse histogram.
__global__ void detect_kernel(const void* ei, int N, int* flag, int* ccnt, int m) {
    int t = threadIdx.x;
    for (int i = t; i < m; i += 256) ccnt[i] = 0;
    if (t < 64) {
        const long long* p64 = (const long long*)ei;
        long long v = p64[t];
        int ok = (v >= 0 && v < (long long)N) ? 1 : 0;
        unsigned long long mask = __ballot(ok);
        if (t == 0) *flag = (__popcll(mask) >= 32) ? 1 : 0;
    }
}

// Decode edge_index to row/col AND build the coarse bucket histogram
// (LDS-first; ~153K global atomics total on a 6.3KB array — L2-resident).
__global__ __launch_bounds__(256) void decode_hist_kernel(const void* ei, int E, int N,
                                                          int NB, const int* flag,
                                                          int* __restrict__ row,
                                                          int* __restrict__ col,
                                                          int* __restrict__ ccnt) {
    __shared__ int hC[NBMAX], hR[NBMAX];
    int t = threadIdx.x;
    for (int b = t; b < NB; b += 256) { hC[b] = 0; hR[b] = 0; }
    __syncthreads();
    int e0 = blockIdx.x * CE;
    int e1 = min(e0 + CE, E);
    bool wide = (*flag != 0);
    for (int i = e0 + t; i < e1; i += 256) {
        int r, c;
        if (wide) {
            const long long* p = (const long long*)ei;
            r = (int)p[i];
            c = (int)p[E + i];
        } else {
            const int* p = (const int*)ei;
            r = p[i];
            c = p[E + i];
        }
        r = min(max(r, 0), N - 1);
        c = min(max(c, 0), N - 1);
        row[i] = r;
        col[i] = c;
        atomicAdd(&hC[c >> 7], 1);
        atomicAdd(&hR[r >> 7], 1);
    }
    __syncthreads();
    for (int b = t; b < NB; b += 256) {
        if (hC[b]) atomicAdd(&ccnt[b], hC[b]);
        if (hR[b]) atomicAdd(&ccnt[NB + b], hR[b]);
    }
}

// Exclusive scan of each NB-segment of ccnt -> cbase (and cursor copy ccur)
__global__ void coarse_scan_kernel(const int* __restrict__ ccnt, int NB,
                                   int* __restrict__ cbase, int* __restrict__ ccur) {
    __shared__ int s[1024];
    int t = threadIdx.x;
    for (int seg = 0; seg < 2; ++seg) {
        int v = (t < NB) ? ccnt[seg * NB + t] : 0;
        s[t] = v;
        __syncthreads();
        for (int d = 1; d < 1024; d <<= 1) {
            int x = (t >= d) ? s[t - d] : 0;
            __syncthreads();
            s[t] += x;
            __syncthreads();
        }
        if (t < NB) {
            int ex = s[t] - v;
            cbase[seg * NB + t] = ex;
            ccur[seg * NB + t]  = ex;
        }
        __syncthreads();
    }
}

// Binned scatter: each block takes CE edges, builds LDS bucket histograms for
// both sorts, reserves per-(block,bucket) space with ONE global atomic, then
// scatters (keyLow, payload) entries into bucket regions.
__global__ __launch_bounds__(256) void binscat_kernel(const int* __restrict__ row,
                                                      const int* __restrict__ col,
                                                      int E, int NB,
                                                      int* __restrict__ ccur,
                                                      int2* __restrict__ b1,
                                                      int2* __restrict__ b2) {
    __shared__ int histC[NBMAX], histR[NBMAX];
    __shared__ int baseC[NBMAX], baseR[NBMAX];
    __shared__ int curC[NBMAX],  curR[NBMAX];
    int t  = threadIdx.x;
    int e0 = blockIdx.x * CE;
    int e1 = min(e0 + CE, E);

    for (int b = t; b < NB; b += 256) { histC[b] = 0; histR[b] = 0; }
    __syncthreads();
    for (int i = e0 + t; i < e1; i += 256) {
        atomicAdd(&histC[col[i] >> 7], 1);
        atomicAdd(&histR[row[i] >> 7], 1);
    }
    __syncthreads();
    for (int b = t; b < NB; b += 256) {
        int hc = histC[b];
        if (hc) baseC[b] = atomicAdd(&ccur[b], hc);
        int hr = histR[b];
        if (hr) baseR[b] = atomicAdd(&ccur[NB + b], hr);
        curC[b] = 0;
        curR[b] = 0;
    }
    __syncthreads();
    for (int i = e0 + t; i < e1; i += 256) {
        int c = col[i], r = row[i];
        int bc = c >> 7, br = r >> 7;
        int rc = atomicAdd(&curC[bc], 1);
        b1[baseC[bc] + rc] = make_int2(c & 127, r);     // (dstLow, src)
        int rr = atomicAdd(&curR[br], 1);
        b2[baseR[br] + rr] = make_int2(r & 127, i);     // (srcLow, eid)
    }
}

// Fused per-bucket build: LDS fine histogram -> LDS scan -> write CSR offsets
// (+dinv for the dst sort) -> scatter entries into the bucket's exclusive
// output window. No global scan, no global atomics.
__global__ __launch_bounds__(256) void build_kernel(const int2* __restrict__ b1,
                                                    const int2* __restrict__ b2,
                                                    const int* __restrict__ cbase,
                                                    const int* __restrict__ ccnt,
                                                    int NB, int N, int E,
                                                    int* __restrict__ doff,
                                                    int* __restrict__ roff,
                                                    float* __restrict__ dinv,
                                                    int* __restrict__ ents,
                                                    int* __restrict__ eid) {
    __shared__ int h[128];
    __shared__ int sc[128];
    __shared__ int cur[128];
    int bi  = blockIdx.x;
    int srt = bi / NB;
    int bk  = bi % NB;
    int t   = threadIdx.x;
    const int2* src = (srt == 0) ? b1 : b2;
    int base  = cbase[bi];
    int count = ccnt[bi];

    if (t < 128) h[t] = 0;
    __syncthreads();
    for (int j = t; j < count; j += 256) atomicAdd(&h[src[base + j].x], 1);
    __syncthreads();
    if (t < 128) sc[t] = h[t];
    __syncthreads();
    for (int d = 1; d < 128; d <<= 1) {
        int x = (t < 128 && t >= d) ? sc[t - d] : 0;
        __syncthreads();
        if (t < 128) sc[t] += x;
        __syncthreads();
    }
    if (t < 128) {
        int node = bk * 128 + t;
        if (node < N) {
            int o = base + sc[t] - h[t];     // exclusive within bucket
            cur[t] = o;
            if (srt == 0) {
                doff[node] = o;
                dinv[node] = rsqrtf((float)(h[t] + 1));   // in-degree + self loop
            } else {
                roff[node] = o;
            }
        }
    }
    if (t == 0 && bk == 0) {
        if (srt == 0) doff[N] = E; else roff[N] = E;
    }
    __syncthreads();
    if (srt == 0) {
        for (int j = t; j < count; j += 256) {
            int2 e = src[base + j];
            int pos = atomicAdd(&cur[e.x], 1);
            ents[pos] = e.y;
        }
    } else {
        for (int j = t; j < count; j += 256) {
            int2 e = src[base + j];
            int pos = atomicAdd(&cur[e.x], 1);
            eid[pos] = e.y;
        }
    }
}

// agg[n] = sum of edge_attr rows over out-edges of n (row-CSR gather).
// Half-wave per edge slot; 4 gathers in flight per half-wave (8 per wave).
__global__ __launch_bounds__(256) void aggr_kernel(const float* __restrict__ ea,
                                                   const int* __restrict__ roff,
                                                   const int* __restrict__ eid,
                                                   int N,
                                                   float* __restrict__ agg) {
    int wid  = threadIdx.x >> 6;
    int lane = threadIdx.x & 63;
    int n = blockIdx.x * 4 + wid;
    if (n >= N) return;
    int f  = lane & 31;
    int hh = lane >> 5;
    int r0 = roff[n];
    int r1 = roff[n + 1];
    float s = 0.f;
    int e = r0 + hh;
    for (; e + 6 < r1; e += 8) {     // each half-wave: e, e+2, e+4, e+6 in flight
        int i0 = eid[e], i1 = eid[e + 2], i2 = eid[e + 4], i3 = eid[e + 6];
        float x0 = ea[(size_t)i0 * F_EDGE + f];
        float x1 = ea[(size_t)i1 * F_EDGE + f];
        float x2 = ea[(size_t)i2 * F_EDGE + f];
        float x3 = ea[(size_t)i3 * F_EDGE + f];
        s += (x0 + x1) + (x2 + x3);
    }
    for (; e < r1; e += 2) s += ea[(size_t)eid[e] * F_EDGE + f];
    s += __shfl(s, lane ^ 32);
    if (hh == 0) agg[(size_t)n * F_EDGE + f] = s;
}

// ---------------------------------------------------------------------------
// GEMM: out[N,F] = concat(A[N,128], B[N,32]) @ W[160,F]
// ---------------------------------------------------------------------------
template <int F, int BN, int TX>
__global__ __launch_bounds__(256) void gemm_kernel(const float* __restrict__ A,
                                                   const float* __restrict__ B,
                                                   const float* __restrict__ W,
                                                   float* __restrict__ outp, int N) {
    constexpr int TY  = 256 / TX;
    constexpr int NPT = BN / TY;
    constexpr int KC  = 32;
    constexpr int IST = KC + 4;
    constexpr int WST = F + 4;
    __shared__ float in_lds[BN][IST];
    __shared__ float w_lds[KC][WST];

    int t  = threadIdx.x;
    int tx = t % TX;
    int ty = t / TX;
    int n0 = blockIdx.x * BN;
    int j0 = tx * 8;

    float acc[NPT][8];
#pragma unroll
    for (int i = 0; i < NPT; ++i)
#pragma unroll
        for (int f = 0; f < 8; ++f) acc[i][f] = 0.f;

    for (int c = 0; c < 5; ++c) {
        const float* src = (c < 4) ? (A + c * KC) : B;
        int stride = (c < 4) ? F_NODE : F_EDGE;
        for (int l = t; l < BN * 8; l += 256) {
            int rr = l >> 3;
            int cc = (l & 7) * 4;
            int n = n0 + rr;
            if (n >= N) n = N - 1;
            float4 v = *(const float4*)(src + (size_t)n * stride + cc);
            *(float4*)&in_lds[rr][cc] = v;
        }
        for (int l = t; l < KC * F / 4; l += 256) {
            int rr = l / (F / 4);
            int cc = (l % (F / 4)) * 4;
            float4 v = *(const float4*)(W + (size_t)(c * KC + rr) * F + cc);
            *(float4*)&w_lds[rr][cc] = v;
        }
        __syncthreads();

#pragma unroll
        for (int kk = 0; kk < KC; kk += 4) {
            float4 a4[NPT];
#pragma unroll
            for (int i = 0; i < NPT; ++i)
                a4[i] = *(const float4*)&in_lds[ty * NPT + i][kk];
#pragma unroll
            for (int p = 0; p < 4; ++p) {
                float4 wa = *(const float4*)&w_lds[kk + p][j0];
                float4 wb = *(const float4*)&w_lds[kk + p][j0 + 4];
#pragma unroll
                for (int i = 0; i < NPT; ++i) {
                    float a = (p == 0) ? a4[i].x : (p == 1) ? a4[i].y
                              : (p == 2) ? a4[i].z : a4[i].w;
                    acc[i][0] = fmaf(a, wa.x, acc[i][0]);
                    acc[i][1] = fmaf(a, wa.y, acc[i][1]);
                    acc[i][2] = fmaf(a, wa.z, acc[i][2]);
                    acc[i][3] = fmaf(a, wa.w, acc[i][3]);
                    acc[i][4] = fmaf(a, wb.x, acc[i][4]);
                    acc[i][5] = fmaf(a, wb.y, acc[i][5]);
                    acc[i][6] = fmaf(a, wb.z, acc[i][6]);
                    acc[i][7] = fmaf(a, wb.w, acc[i][7]);
                }
            }
        }
        __syncthreads();
    }

#pragma unroll
    for (int i = 0; i < NPT; ++i) {
        int n = n0 + ty * NPT + i;
        if (n < N) {
            *(float4*)(outp + (size_t)n * F + j0) =
                make_float4(acc[i][0], acc[i][1], acc[i][2], acc[i][3]);
            *(float4*)(outp + (size_t)n * F + j0 + 4) =
                make_float4(acc[i][4], acc[i][5], acc[i][6], acc[i][7]);
        }
    }
}

// ---------------------------------------------------------------------------
// Conv aggregation: out[n] = sum_{e: dst==n} dinv[src]*dinv[n]*h[src] +
//                   dinv[n]^2*h[n] + bias.  Norm computed on the fly.
// One wave per node; CSR gather, 8 gathers in flight.
// ---------------------------------------------------------------------------
template <int F, bool RELU>
__global__ __launch_bounds__(256) void conv_kernel(const float* __restrict__ h,
                                                   const int* __restrict__ doff,
                                                   const int* __restrict__ ents,
                                                   const float* __restrict__ dinv,
                                                   const float* __restrict__ bias,
                                                   float* __restrict__ outp, int N) {
    int wid  = threadIdx.x >> 6;
    int lane = threadIdx.x & 63;
    int n = blockIdx.x * 4 + wid;
    if (n >= N) return;
    float dn = dinv[n];
    float sw = dn * dn;
    int e0 = doff[n], e1 = doff[n + 1];

    if constexpr (F == 128) {
        float2 hv = *((const float2*)(h + (size_t)n * F) + lane);
        float a0 = sw * hv.x, a1 = sw * hv.y;
        int e = e0;
        for (; e + 8 <= e1; e += 8) {
            int s0 = ents[e],     s1 = ents[e + 1], s2 = ents[e + 2], s3 = ents[e + 3];
            int s4 = ents[e + 4], s5 = ents[e + 5], s6 = ents[e + 6], s7 = ents[e + 7];
            float2 v0 = *((const float2*)(h + (size_t)s0 * F) + lane);
            float2 v1 = *((const float2*)(h + (size_t)s1 * F) + lane);
            float2 v2 = *((const float2*)(h + (size_t)s2 * F) + lane);
            float2 v3 = *((const float2*)(h + (size_t)s3 * F) + lane);
            float2 v4 = *((const float2*)(h + (size_t)s4 * F) + lane);
            float2 v5 = *((const float2*)(h + (size_t)s5 * F) + lane);
            float2 v6 = *((const float2*)(h + (size_t)s6 * F) + lane);
            float2 v7 = *((const float2*)(h + (size_t)s7 * F) + lane);
            float w0 = dinv[s0] * dn, w1 = dinv[s1] * dn;
            float w2 = dinv[s2] * dn, w3 = dinv[s3] * dn;
            float w4 = dinv[s4] * dn, w5 = dinv[s5] * dn;
            float w6 = dinv[s6] * dn, w7 = dinv[s7] * dn;
            a0 = fmaf(w0, v0.x, a0); a1 = fmaf(w0, v0.y, a1);
            a0 = fmaf(w1, v1.x, a0); a1 = fmaf(w1, v1.y, a1);
            a0 = fmaf(w2, v2.x, a0); a1 = fmaf(w2, v2.y, a1);
            a0 = fmaf(w3, v3.x, a0); a1 = fmaf(w3, v3.y, a1);
            a0 = fmaf(w4, v4.x, a0); a1 = fmaf(w4, v4.y, a1);
            a0 = fmaf(w5, v5.x, a0); a1 = fmaf(w5, v5.y, a1);
            a0 = fmaf(w6, v6.x, a0); a1 = fmaf(w6, v6.y, a1);
            a0 = fmaf(w7, v7.x, a0); a1 = fmaf(w7, v7.y, a1);
        }
        for (; e + 4 <= e1; e += 4) {
            int s0 = ents[e], s1 = ents[e + 1], s2 = ents[e + 2], s3 = ents[e + 3];
            float2 v0 = *((const float2*)(h + (size_t)s0 * F) + lane);
            float2 v1 = *((const float2*)(h + (size_t)s1 * F) + lane);
            float2 v2 = *((const float2*)(h + (size_t)s2 * F) + lane);
            float2 v3 = *((const float2*)(h + (size_t)s3 * F) + lane);
            float w0 = dinv[s0] * dn, w1 = dinv[s1] * dn;
            float w2 = dinv[s2] * dn, w3 = dinv[s3] * dn;
            a0 = fmaf(w0, v0.x, a0); a1 = fmaf(w0, v0.y, a1);
            a0 = fmaf(w1, v1.x, a0); a1 = fmaf(w1, v1.y, a1);
            a0 = fmaf(w2, v2.x, a0); a1 = fmaf(w2, v2.y, a1);
            a0 = fmaf(w3, v3.x, a0); a1 = fmaf(w3, v3.y, a1);
        }
        for (; e < e1; ++e) {
            int s = ents[e];
            float w = dinv[s] * dn;
            float2 v = *((const float2*)(h + (size_t)s * F) + lane);
            a0 = fmaf(w, v.x, a0);
            a1 = fmaf(w, v.y, a1);
        }
        float2 bv = *((const float2*)bias + lane);
        a0 += bv.x;
        a1 += bv.y;
        if (RELU) { a0 = fmaxf(a0, 0.f); a1 = fmaxf(a1, 0.f); }
        *((float2*)(outp + (size_t)n * F) + lane) = make_float2(a0, a1);
    } else {
        float a0 = sw * h[(size_t)n * F + lane];
        int e = e0;
        for (; e + 8 <= e1; e += 8) {
            int s0 = ents[e],     s1 = ents[e + 1], s2 = ents[e + 2], s3 = ents[e + 3];
            int s4 = ents[e + 4], s5 = ents[e + 5], s6 = ents[e + 6], s7 = ents[e + 7];
            float v0 = h[(size_t)s0 * F + lane];
            float v1 = h[(size_t)s1 * F + lane];
            float v2 = h[(size_t)s2 * F + lane];
            float v3 = h[(size_t)s3 * F + lane];
            float v4 = h[(size_t)s4 * F + lane];
            float v5 = h[(size_t)s5 * F + lane];
            float v6 = h[(size_t)s6 * F + lane];
            float v7 = h[(size_t)s7 * F + lane];
            a0 = fmaf(dinv[s0] * dn, v0, a0);
            a0 = fmaf(dinv[s1] * dn, v1, a0);
            a0 = fmaf(dinv[s2] * dn, v2, a0);
            a0 = fmaf(dinv[s3] * dn, v3, a0);
            a0 = fmaf(dinv[s4] * dn, v4, a0);
            a0 = fmaf(dinv[s5] * dn, v5, a0);
            a0 = fmaf(dinv[s6] * dn, v6, a0);
            a0 = fmaf(dinv[s7] * dn, v7, a0);
        }
        for (; e + 4 <= e1; e += 4) {
            int s0 = ents[e], s1 = ents[e + 1], s2 = ents[e + 2], s3 = ents[e + 3];
            float v0 = h[(size_t)s0 * F + lane];
            float v1 = h[(size_t)s1 * F + lane];
            float v2 = h[(size_t)s2 * F + lane];
            float v3 = h[(size_t)s3 * F + lane];
            a0 = fmaf(dinv[s0] * dn, v0, a0);
            a0 = fmaf(dinv[s1] * dn, v1, a0);
            a0 = fmaf(dinv[s2] * dn, v2, a0);
            a0 = fmaf(dinv[s3] * dn, v3, a0);
        }
        for (; e < e1; ++e) {
            int s = ents[e];
            a0 = fmaf(dinv[s] * dn, h[(size_t)s * F + lane], a0);
        }
        a0 += bias[lane];
        if (RELU) a0 = fmaxf(a0, 0.f);
        outp[(size_t)n * F + lane] = a0;
    }
}

// ---------------------------------------------------------------------------
extern "C" void kernel_launch(void* const* d_in, const int* in_sizes, int n_in,
                              void* d_out, int out_size, void* d_ws, size_t ws_size,
                              hipStream_t stream) {
    const float* x  = (const float*)d_in[0];
    const void*  ei = d_in[1];
    const float* ea = (const float*)d_in[2];
    const float* w1 = (const float*)d_in[3];
    const float* b1 = (const float*)d_in[4];
    const float* w2 = (const float*)d_in[5];
    const float* b2 = (const float*)d_in[6];
    float* out = (float*)d_out;

    int N = in_sizes[0] / F_NODE;
    int E = in_sizes[1] / 2;
    int NB = (N + 127) >> 7;              // coarse buckets (782 for N=100K)

    char* ws = (char*)d_ws;
    size_t off = 0;
    auto alloc = [&](size_t bytes) -> void* {
        void* p = ws + off;
        off = (off + bytes + 255) & ~(size_t)255;
        return p;
    };

    int*   flag  = (int*)alloc(256);
    int*   row   = (int*)alloc((size_t)E * 4);
    int*   col   = (int*)alloc((size_t)E * 4);
    int*   ccnt  = (int*)alloc((size_t)2 * NBMAX * 4);
    int*   cbase = (int*)alloc((size_t)2 * NBMAX * 4);
    int*   ccur  = (int*)alloc((size_t)2 * NBMAX * 4);
    int*   doff  = (int*)alloc((size_t)(N + 1) * 4);
    int*   roff  = (int*)alloc((size_t)(N + 1) * 4);
    float* dinv  = (float*)alloc((size_t)N * 4);
    int*   ents  = (int*)alloc((size_t)E * 4);
    int*   eid   = (int*)alloc((size_t)E * 4);
    float* agg   = (float*)alloc((size_t)N * F_EDGE * 4);
    float* h1    = (float*)alloc((size_t)N * HID * 4);
    float* hr    = (float*)alloc((size_t)N * HID * 4);
    float* h2    = (float*)alloc((size_t)N * OUTF * 4);

    // Bucket staging arrays alias h1 (dead until gemm1, which runs after build).
    int2* bkt1 = (int2*)h1;                       // E * 8 bytes
    int2* bkt2 = (int2*)(h1 + (size_t)2 * E);     // E * 8 bytes (h1 = 51.2MB >= 25.6MB)

    int nChunk = (E + CE - 1) / CE;

    detect_kernel<<<1, 256, 0, stream>>>(ei, N, flag, ccnt, 2 * NB);
    decode_hist_kernel<<<nChunk, 256, 0, stream>>>(ei, E, N, NB, flag, row, col, ccnt);
    coarse_scan_kernel<<<1, 1024, 0, stream>>>(ccnt, NB, cbase, ccur);
    binscat_kernel<<<nChunk, 256, 0, stream>>>(row, col, E, NB, ccur, bkt1, bkt2);
    build_kernel<<<2 * NB, 256, 0, stream>>>(bkt1, bkt2, cbase, ccnt, NB, N, E,
                                             doff, roff, dinv, ents, eid);
    aggr_kernel<<<(N + 3) / 4, 256, 0, stream>>>(ea, roff, eid, N, agg);

    gemm_kernel<HID, 128, 16><<<(N + 127) / 128, 256, 0, stream>>>(x, agg, w1, h1, N);
    conv_kernel<HID, true><<<(N + 3) / 4, 256, 0, stream>>>(h1, doff, ents, dinv, b1, hr, N);
    gemm_kernel<OUTF, 256, 8><<<(N + 255) / 256, 256, 0, stream>>>(hr, agg, w2, h2, N);
    conv_kernel<OUTF, false><<<(N + 3) / 4, 256, 0, stream>>>(h2, doff, ents, dinv, b2, out, N);
}